// Round 5
// baseline (147.942 us; speedup 1.0000x reference)
//
#include <hip/hip_runtime.h>
#include <hip/hip_bf16.h>

typedef __attribute__((ext_vector_type(8))) __bf16 bf16x8;
typedef __attribute__((ext_vector_type(4))) float f32x4;

#define MFMA(a,b,c) __builtin_amdgcn_mfma_f32_16x16x32_bf16((a),(b),(c),0,0,0)

// LDS layout (48 KB total -> 3 blocks/CU, 24 waves):
//  XB 0..16K   : x [64][128] bf16 (swz256) -> P heads 0,1 -> ob [64][128]
//  QB 16K..32K : q [64][128] bf16 (swz256) -> P heads 2,3
//  KB 32K..48K : k [64][128] bf16 (swz256) -> v^T [128][64] (swz128)
// P head h lives at byte offset h*8192 (contiguous across XB..QB).
#define XB 0u
#define QB 16384u
#define KB 32768u

static __device__ __forceinline__ unsigned short f2u(float x) {
  return __builtin_bit_cast(unsigned short, static_cast<__bf16>(x));
}
static __device__ __forceinline__ unsigned long long pack4(float a, float b, float c, float d) {
  return (unsigned long long)f2u(a) | ((unsigned long long)f2u(b) << 16) |
         ((unsigned long long)f2u(c) << 32) | ((unsigned long long)f2u(d) << 48);
}
static __device__ __forceinline__ unsigned long long pack4v(f32x4 v) {
  return pack4(v[0], v[1], v[2], v[3]);
}
static __device__ __forceinline__ unsigned sw256(unsigned row, unsigned colb) {
  return (row << 8) + (colb ^ ((row & 7u) << 4));
}
static __device__ __forceinline__ unsigned sw128(unsigned row, unsigned colb) {
  return (row << 7) + (colb ^ ((row & 7u) << 4));
}

// ---------------- prep: weights -> bf16, bias gather -> padded [4][64][64] ----------------
__global__ void rsa_prep(const float* __restrict__ qk_w, const float* __restrict__ v_w,
                         const float* __restrict__ proj_w, const float* __restrict__ bias_table,
                         unsigned short* __restrict__ wqk, unsigned short* __restrict__ wv,
                         unsigned short* __restrict__ wp, float* __restrict__ biasNN) {
  int t = blockIdx.x * blockDim.x + threadIdx.x;
  int stride = gridDim.x * blockDim.x;
  for (int i = t; i < 256 * 128; i += stride) wqk[i] = f2u(qk_w[i]);
  for (int i = t; i < 128 * 128; i += stride) wv[i] = f2u(v_w[i]);
  for (int i = t; i < 128 * 128; i += stride) wp[i] = f2u(proj_w[i]);
  for (int i = t; i < 4 * 64 * 64; i += stride) {
    int h = i >> 12, r = (i >> 6) & 63, m = i & 63;
    float v = -1e9f;
    if (r < 49 && m < 49) {
      int ri = r / 7, rj = r - ri * 7, mi = m / 7, mj = m - mi * 7;
      int rel = (ri - mi + 6) * 13 + (rj - mj + 6);
      v = bias_table[rel * 4 + h];
    }
    biasNN[i] = v;
  }
}

// ---------------- main: one window per block, 8 waves, 48KB LDS ----------------
__global__ __launch_bounds__(512, 2) void rsa_main(
    const float* __restrict__ x, const float* __restrict__ qk_bias,
    const float* __restrict__ v_bias, const float* __restrict__ proj_bias,
    const unsigned short* __restrict__ wqk, const unsigned short* __restrict__ wv,
    const unsigned short* __restrict__ wp, const float* __restrict__ biasNN,
    float* __restrict__ out) {
  __shared__ __align__(16) unsigned char LDS[49152];
  const int tid = threadIdx.x;
  const int w = tid >> 6;
  const int lane = tid & 63;
  const int c = lane & 15;
  const int g = lane >> 4;
  const int b = blockIdx.x;
  const int h = w >> 1;
  const int rt0 = (w & 1) * 2;
  const float SCALE = 0.17677669529663687f;  // 32^-0.5

  // Phase 0: stage x (49x128 f32) -> bf16 LDS [64][128] swizzled, zero-pad rows 49..63
  {
    const f32x4* xp = reinterpret_cast<const f32x4*>(x + (size_t)b * 6272);
    for (int i = tid; i < 1568; i += 512) {
      f32x4 v = xp[i];
      unsigned row = (unsigned)i >> 5, c4 = (unsigned)i & 31u;
      *reinterpret_cast<unsigned long long*>(LDS + XB + sw256(row, c4 * 8)) = pack4v(v);
    }
    for (int i = tid; i < 480; i += 512) {
      unsigned row = 49 + ((unsigned)i >> 5), c4 = (unsigned)i & 31u;
      *reinterpret_cast<unsigned long long*>(LDS + XB + sw256(row, c4 * 8)) = 0ull;
    }
  }
  __syncthreads();  // B1: x visible

  // Phase 1 (fused QKV, ks-outer): each xf read feeds 3 MFMAs.
  // q,k written to LDS now; accv HELD IN AGPRS until after the S-MFMAs
  // (frees the 16KB VT region -> 48KB total -> 3 blocks/CU).
  f32x4 accv[4];
  {
    f32x4 accq[4], acck[4];
#pragma unroll
    for (int nt = 0; nt < 4; ++nt) {
      accq[nt] = f32x4{0.f, 0.f, 0.f, 0.f};
      acck[nt] = f32x4{0.f, 0.f, 0.f, 0.f};
      accv[nt] = f32x4{0.f, 0.f, 0.f, 0.f};
    }
    const unsigned short* rq = wqk + (w * 16 + c) * 128 + g * 8;
    const unsigned short* rk = wqk + (128 + w * 16 + c) * 128 + g * 8;
    const unsigned short* rv = wv + (w * 16 + c) * 128 + g * 8;
#pragma unroll
    for (int ks = 0; ks < 4; ++ks) {
      bf16x8 aw = *reinterpret_cast<const bf16x8*>(rq + ks * 32);
      bf16x8 kw = *reinterpret_cast<const bf16x8*>(rk + ks * 32);
      bf16x8 vw = *reinterpret_cast<const bf16x8*>(rv + ks * 32);
#pragma unroll
      for (int nt = 0; nt < 4; ++nt) {
        bf16x8 xf = *reinterpret_cast<const bf16x8*>(LDS + XB + sw256(nt * 16 + c, (ks * 32 + g * 8) * 2));
        accq[nt] = MFMA(aw, xf, accq[nt]);
        acck[nt] = MFMA(kw, xf, acck[nt]);
        accv[nt] = MFMA(xf, vw, accv[nt]);
      }
    }
    const f32x4 qb4 = *reinterpret_cast<const f32x4*>(qk_bias + w * 16 + g * 4);
    const f32x4 kb4 = *reinterpret_cast<const f32x4*>(qk_bias + 128 + w * 16 + g * 4);
#pragma unroll
    for (int nt = 0; nt < 4; ++nt) {
      const unsigned tok = nt * 16 + c;
      const unsigned cb = (w * 16 + g * 4) * 2;
      *reinterpret_cast<unsigned long long*>(LDS + QB + sw256(tok, cb)) =
          pack4((accq[nt][0] + qb4[0]) * SCALE, (accq[nt][1] + qb4[1]) * SCALE,
                (accq[nt][2] + qb4[2]) * SCALE, (accq[nt][3] + qb4[3]) * SCALE);
      *reinterpret_cast<unsigned long long*>(LDS + KB + sw256(tok, cb)) =
          pack4(acck[nt][0] + kb4[0], acck[nt][1] + kb4[1],
                acck[nt][2] + kb4[2], acck[nt][3] + kb4[3]);
    }
  }
  __syncthreads();  // B2: q,k visible (x still live in XB)

  // Phase 2a: S^T = K @ Q^T per head (wave pair h; rows rt0, rt0+1), kf hoisted.
  // Bias rows prefetched first so L2 latency hides under MFMAs.
  f32x4 bb[2][4];
#pragma unroll
  for (int r2 = 0; r2 < 2; ++r2) {
    const int r = (rt0 + r2) * 16 + c;
    const float* bp = biasNN + ((h * 64 + r) << 6);
#pragma unroll
    for (int mt = 0; mt < 4; ++mt)
      bb[r2][mt] = *reinterpret_cast<const f32x4*>(bp + mt * 16 + g * 4);
  }
  f32x4 s[2][4];
  {
    bf16x8 kf[4];
#pragma unroll
    for (int mt = 0; mt < 4; ++mt)
      kf[mt] = *reinterpret_cast<const bf16x8*>(LDS + KB + sw256(mt * 16 + c, h * 64 + g * 16));
#pragma unroll
    for (int r2 = 0; r2 < 2; ++r2) {
      bf16x8 qf = *reinterpret_cast<const bf16x8*>(LDS + QB + sw256((rt0 + r2) * 16 + c, h * 64 + g * 16));
#pragma unroll
      for (int mt = 0; mt < 4; ++mt) {
        f32x4 z = {0.f, 0.f, 0.f, 0.f};
        s[r2][mt] = MFMA(kf[mt], qf, z);
      }
    }
  }
  __syncthreads();  // B3: all QB/KB/XB reads done -> regions recyclable

  // Phase 2b: write V^T (from AGPRs) over KB; softmax; write P at h*8192 (over x,q).
  {
    const float vb = v_bias[w * 16 + c];
#pragma unroll
    for (int nt = 0; nt < 4; ++nt)
      *reinterpret_cast<unsigned long long*>(LDS + KB + sw128(w * 16 + c, (nt * 16 + g * 4) * 2)) =
          pack4(accv[nt][0] + vb, accv[nt][1] + vb, accv[nt][2] + vb, accv[nt][3] + vb);
  }
#pragma unroll
  for (int r2 = 0; r2 < 2; ++r2) {
    const int r = (rt0 + r2) * 16 + c;
    float v[16];
    float sum = 0.f;
#pragma unroll
    for (int mt = 0; mt < 4; ++mt) {
#pragma unroll
      for (int j = 0; j < 4; ++j) {
        v[mt * 4 + j] = __expf(s[r2][mt][j] + bb[r2][mt][j]);
        sum += v[mt * 4 + j];
      }
    }
    sum += __shfl_xor(sum, 16);
    sum += __shfl_xor(sum, 32);
    const float inv = (sum > 0.f) ? 1.0f / sum : 0.f;
#pragma unroll
    for (int mt = 0; mt < 4; ++mt)
      *reinterpret_cast<unsigned long long*>(LDS + (unsigned)(h * 8192) + sw128(r, (mt * 16 + g * 4) * 2)) =
          pack4(v[mt * 4] * inv, v[mt * 4 + 1] * inv, v[mt * 4 + 2] * inv, v[mt * 4 + 3] * inv);
  }
  __syncthreads();  // B4: VT + P visible

  // Phase 2c: O^T = V^T @ P^T with af/pf register blocks (8 reads, 8 MFMAs) -> regs
  f32x4 ob[2][2];
  {
    bf16x8 af[2][2], pf[2][2];
#pragma unroll
    for (int dt = 0; dt < 2; ++dt)
#pragma unroll
      for (int ks = 0; ks < 2; ++ks)
        af[dt][ks] = *reinterpret_cast<const bf16x8*>(LDS + KB + sw128(h * 32 + dt * 16 + c, (ks * 32 + g * 8) * 2));
#pragma unroll
    for (int r2 = 0; r2 < 2; ++r2)
#pragma unroll
      for (int ks = 0; ks < 2; ++ks)
        pf[r2][ks] = *reinterpret_cast<const bf16x8*>(LDS + (unsigned)(h * 8192) + sw128((rt0 + r2) * 16 + c, (ks * 32 + g * 8) * 2));
#pragma unroll
    for (int dt = 0; dt < 2; ++dt)
#pragma unroll
      for (int r2 = 0; r2 < 2; ++r2) {
        f32x4 acc = {0.f, 0.f, 0.f, 0.f};
        acc = MFMA(af[dt][0], pf[r2][0], acc);
        acc = MFMA(af[dt][1], pf[r2][1], acc);
        ob[dt][r2] = acc;
      }
  }
  __syncthreads();  // B5: P reads done -> XB recyclable (WAR)

  // write ob -> XB
#pragma unroll
  for (int dt = 0; dt < 2; ++dt)
#pragma unroll
    for (int r2 = 0; r2 < 2; ++r2) {
      const int r = (rt0 + r2) * 16 + c;
      *reinterpret_cast<unsigned long long*>(LDS + XB + sw256(r, (h * 32 + dt * 16 + g * 4) * 2)) =
          pack4v(ob[dt][r2]);
    }
  __syncthreads();  // B6: ob visible

  // Phase 3: out^T = Wp @ O^T; wave w owns 2x2 tile (nt0..nt0+1) x (ch0..ch0+1),
  // each bf read feeds 2 MFMAs.
  {
    const int nt0 = (w >> 2) * 2;
    const int ch0 = (w & 3) * 2;
    bf16x8 ap[2][4];
#pragma unroll
    for (int u = 0; u < 2; ++u) {
      const unsigned short* rp = wp + ((ch0 + u) * 16 + c) * 128 + g * 8;
#pragma unroll
      for (int ks = 0; ks < 4; ++ks) ap[u][ks] = *reinterpret_cast<const bf16x8*>(rp + ks * 32);
    }
    f32x4 pbu[2];
#pragma unroll
    for (int u = 0; u < 2; ++u)
      pbu[u] = *reinterpret_cast<const f32x4*>(proj_bias + (ch0 + u) * 16 + g * 4);
#pragma unroll
    for (int t2 = 0; t2 < 2; ++t2) {
      const int nt = nt0 + t2;
      bf16x8 bf[4];
#pragma unroll
      for (int ks = 0; ks < 4; ++ks)
        bf[ks] = *reinterpret_cast<const bf16x8*>(LDS + XB + sw256(nt * 16 + c, (ks * 32 + g * 8) * 2));
      const int tok = nt * 16 + c;
#pragma unroll
      for (int u = 0; u < 2; ++u) {
        f32x4 acc = {0.f, 0.f, 0.f, 0.f};
#pragma unroll
        for (int ks = 0; ks < 4; ++ks) acc = MFMA(ap[u][ks], bf[ks], acc);
        if (tok < 49) {
          f32x4 o = {acc[0] + pbu[u][0], acc[1] + pbu[u][1],
                     acc[2] + pbu[u][2], acc[3] + pbu[u][3]};
          *reinterpret_cast<f32x4*>(out + ((size_t)b * 49 + tok) * 128 + (ch0 + u) * 16 + g * 4) = o;
        }
      }
    }
  }
}

extern "C" void kernel_launch(void* const* d_in, const int* in_sizes, int n_in,
                              void* d_out, int out_size, void* d_ws, size_t ws_size,
                              hipStream_t stream) {
  const float* x          = (const float*)d_in[0];
  const float* qk_w       = (const float*)d_in[1];
  const float* qk_b       = (const float*)d_in[2];
  const float* v_w        = (const float*)d_in[3];
  const float* v_b        = (const float*)d_in[4];
  const float* proj_w     = (const float*)d_in[5];
  const float* proj_b     = (const float*)d_in[6];
  const float* bias_table = (const float*)d_in[7];
  float* out = (float*)d_out;

  // workspace carve: wqk bf16 [256*128] | wv [128*128] | wp [128*128] | biasNN f32 [4*64*64]
  unsigned short* wqk = (unsigned short*)d_ws;
  unsigned short* wv  = wqk + 256 * 128;
  unsigned short* wp  = wv + 128 * 128;
  float* biasNN = (float*)((char*)d_ws + 131072);

  const int B = in_sizes[0] / (49 * 128);

  rsa_prep<<<dim3(128), dim3(512), 0, stream>>>(qk_w, v_w, proj_w, bias_table, wqk, wv, wp, biasNN);
  rsa_main<<<dim3(B), dim3(512), 0, stream>>>(x, qk_b, v_b, proj_b, wqk, wv, wp, biasNN, out);
}

// Round 6
// 123.032 us; speedup vs baseline: 1.2025x; 1.2025x over previous
//
#include <hip/hip_runtime.h>
#include <hip/hip_bf16.h>

typedef __attribute__((ext_vector_type(8))) __bf16 bf16x8;
typedef __attribute__((ext_vector_type(4))) float f32x4;

#define MFMA(a,b,c) __builtin_amdgcn_mfma_f32_16x16x32_bf16((a),(b),(c),0,0,0)

// LDS layout (64 KB total, static):
//  XB 0..16K   : x  [64][128] bf16 (swz) -> later ob [64][128] (attention out)
//  QB 16K..32K : q  [64][128] bf16 (swz) -> later P heads 0,1
//  KB 32K..48K : k  [64][128] bf16 (swz) -> later P heads 2,3
//  VT 48K..64K : v^T [128][64] bf16 (swz)
#define XB 0u
#define QB 16384u
#define KB 32768u
#define VT 49152u

static __device__ __forceinline__ unsigned short f2u(float x) {
  return __builtin_bit_cast(unsigned short, static_cast<__bf16>(x));
}
// cvt_pk-friendly pack: plain __bf16 casts let the compiler emit
// v_cvt_pk_bf16_f32 (2 floats/inst) instead of scalar cvt + shift/or chains.
static __device__ __forceinline__ unsigned long long pack4(float a, float b, float c, float d) {
  union { __bf16 h[4]; unsigned long long u; } z;
  z.h[0] = static_cast<__bf16>(a);
  z.h[1] = static_cast<__bf16>(b);
  z.h[2] = static_cast<__bf16>(c);
  z.h[3] = static_cast<__bf16>(d);
  return z.u;
}
static __device__ __forceinline__ unsigned long long pack4v(f32x4 v) {
  return pack4(v[0], v[1], v[2], v[3]);
}
static __device__ __forceinline__ unsigned sw256(unsigned row, unsigned colb) {
  return (row << 8) + (colb ^ ((row & 7u) << 4));
}
static __device__ __forceinline__ unsigned sw128(unsigned row, unsigned colb) {
  return (row << 7) + (colb ^ ((row & 7u) << 4));
}

// ---------------- prep: weights -> bf16 (Wq pre-scaled), bias gather ----------------
__global__ void rsa_prep(const float* __restrict__ qk_w, const float* __restrict__ v_w,
                         const float* __restrict__ proj_w, const float* __restrict__ bias_table,
                         unsigned short* __restrict__ wqk, unsigned short* __restrict__ wv,
                         unsigned short* __restrict__ wp, float* __restrict__ biasNN) {
  const float SCALE = 0.17677669529663687f;  // 32^-0.5, folded into Wq
  int t = blockIdx.x * blockDim.x + threadIdx.x;
  int stride = gridDim.x * blockDim.x;
  for (int i = t; i < 256 * 128; i += stride) {
    float v = qk_w[i];
    if (i < 128 * 128) v *= SCALE;           // q-half pre-scaled
    wqk[i] = f2u(v);
  }
  for (int i = t; i < 128 * 128; i += stride) wv[i] = f2u(v_w[i]);
  for (int i = t; i < 128 * 128; i += stride) wp[i] = f2u(proj_w[i]);
  for (int i = t; i < 4 * 64 * 64; i += stride) {
    int h = i >> 12, r = (i >> 6) & 63, m = i & 63;
    float v = -1e9f;
    if (r < 49 && m < 49) {
      int ri = r / 7, rj = r - ri * 7, mi = m / 7, mj = m - mi * 7;
      int rel = (ri - mi + 6) * 13 + (rj - mj + 6);
      v = bias_table[rel * 4 + h];
    }
    biasNN[i] = v;
  }
}

// ---------------- main: one window per block, 8 waves (round-0 structure) ----------------
__global__ __launch_bounds__(512, 4) void rsa_main(
    const float* __restrict__ x, const float* __restrict__ qk_bias,
    const float* __restrict__ v_bias, const float* __restrict__ proj_bias,
    const unsigned short* __restrict__ wqk, const unsigned short* __restrict__ wv,
    const unsigned short* __restrict__ wp, const float* __restrict__ biasNN,
    float* __restrict__ out) {
  __shared__ __align__(16) unsigned char LDS[65536];
  const int tid = threadIdx.x;
  const int w = tid >> 6;
  const int lane = tid & 63;
  const int c = lane & 15;
  const int g = lane >> 4;
  const int b = blockIdx.x;
  const float SCALE = 0.17677669529663687f;  // only for the q-bias now

  // Phase 0: stage x (49x128 f32) -> bf16 LDS [64][128] swizzled, zero-pad rows 49..63
  {
    const f32x4* xp = reinterpret_cast<const f32x4*>(x + (size_t)b * 6272);
    for (int i = tid; i < 1568; i += 512) {
      f32x4 v = xp[i];
      unsigned row = (unsigned)i >> 5, c4 = (unsigned)i & 31u;
      *reinterpret_cast<unsigned long long*>(LDS + XB + sw256(row, c4 * 8)) = pack4v(v);
    }
    for (int i = tid; i < 480; i += 512) {
      unsigned row = 49 + ((unsigned)i >> 5), c4 = (unsigned)i & 31u;
      *reinterpret_cast<unsigned long long*>(LDS + XB + sw256(row, c4 * 8)) = 0ull;
    }
  }
  __syncthreads();  // B1: x visible

  // Phase 1a: [q;k]^T = Wqk @ X^T (output-transposed). Wave w: chout tiles {w, w+8}.
  __builtin_amdgcn_s_setprio(1);
#pragma unroll
  for (int mi = 0; mi < 2; ++mi) {
    const int mt = w + 8 * mi;  // chout tile 0..15 over 256 outputs
    bf16x8 a[4];
    const unsigned short* wrow = wqk + (mt * 16 + c) * 128 + g * 8;
#pragma unroll
    for (int ks = 0; ks < 4; ++ks) a[ks] = *reinterpret_cast<const bf16x8*>(wrow + ks * 32);
    const int chout = mt * 16 + g * 4;
    f32x4 bias4 = *reinterpret_cast<const f32x4*>(qk_bias + chout);
    if (mi == 0) { bias4[0] *= SCALE; bias4[1] *= SCALE; bias4[2] *= SCALE; bias4[3] *= SCALE; }
#pragma unroll
    for (int nt = 0; nt < 4; ++nt) {
      f32x4 acc = {0.f, 0.f, 0.f, 0.f};
#pragma unroll
      for (int ks = 0; ks < 4; ++ks) {
        bf16x8 bf = *reinterpret_cast<const bf16x8*>(LDS + XB + sw256(nt * 16 + c, (ks * 32 + g * 8) * 2));
        acc = MFMA(a[ks], bf, acc);
      }
      const unsigned tok = nt * 16 + c;
      const unsigned colb = ((mt & 7) * 16 + g * 4) * 2;
      const unsigned base = (mi == 0) ? QB : KB;
      *reinterpret_cast<unsigned long long*>(LDS + base + sw256(tok, colb)) =
          pack4(acc[0] + bias4[0], acc[1] + bias4[1], acc[2] + bias4[2], acc[3] + bias4[3]);
    }
  }

  // Phase 1b: V = X @ Wv^T (normal orientation), stored transposed vtb[ch][tok]
  {
    const float vb = v_bias[w * 16 + c];
    bf16x8 bw[4];
    const unsigned short* wrow = wv + (w * 16 + c) * 128 + g * 8;
#pragma unroll
    for (int ks = 0; ks < 4; ++ks) bw[ks] = *reinterpret_cast<const bf16x8*>(wrow + ks * 32);
#pragma unroll
    for (int mt = 0; mt < 4; ++mt) {
      f32x4 acc = {0.f, 0.f, 0.f, 0.f};
#pragma unroll
      for (int ks = 0; ks < 4; ++ks) {
        bf16x8 af = *reinterpret_cast<const bf16x8*>(LDS + XB + sw256(mt * 16 + c, (ks * 32 + g * 8) * 2));
        acc = MFMA(af, bw[ks], acc);
      }
      const unsigned row = w * 16 + c;              // channel
      const unsigned colb = (mt * 16 + g * 4) * 2;  // token byte offset
      *reinterpret_cast<unsigned long long*>(LDS + VT + sw128(row, colb)) =
          pack4(acc[0] + vb, acc[1] + vb, acc[2] + vb, acc[3] + vb);
    }
  }
  __builtin_amdgcn_s_setprio(0);
  __syncthreads();  // B2: q,k,vt visible

  // Phase 2a: S^T = K @ Q^T per head (wave pair: h = w>>1, half = w&1 owns rt {2h..})
  const int h = w >> 1;
  const int rt0 = (w & 1) * 2;

  // Bias rows prefetched BEFORE the S-MFMAs (independent of LDS) so the ~300cy
  // L2 latency hides under the MFMA cluster instead of stalling the softmax.
  f32x4 bb[2][4];
#pragma unroll
  for (int r2 = 0; r2 < 2; ++r2) {
    const int r = (rt0 + r2) * 16 + c;
    const float* bp = biasNN + ((h * 64 + r) << 6);
#pragma unroll
    for (int mt = 0; mt < 4; ++mt)
      bb[r2][mt] = *reinterpret_cast<const f32x4*>(bp + mt * 16 + g * 4);
  }

  f32x4 s[2][4];
  __builtin_amdgcn_s_setprio(1);
#pragma unroll
  for (int r2 = 0; r2 < 2; ++r2) {
    const int rt = rt0 + r2;
    bf16x8 qf = *reinterpret_cast<const bf16x8*>(LDS + QB + sw256(rt * 16 + c, h * 64 + g * 16));
#pragma unroll
    for (int mt = 0; mt < 4; ++mt) {
      bf16x8 kf = *reinterpret_cast<const bf16x8*>(LDS + KB + sw256(mt * 16 + c, h * 64 + g * 16));
      f32x4 z = {0.f, 0.f, 0.f, 0.f};
      s[r2][mt] = MFMA(kf, qf, z);
    }
  }
  __builtin_amdgcn_s_setprio(0);
  __syncthreads();  // B3: q/k now dead; their LDS becomes P

  // Phase 2b: softmax along m (no max subtraction: logits O(1) by construction;
  // pad bias -1e9 -> exp=0; pad rows sum=0 -> inv guarded to 0). P -> QB+h*8192.
#pragma unroll
  for (int r2 = 0; r2 < 2; ++r2) {
    const int r = (rt0 + r2) * 16 + c;
    float v[16];
    float sum = 0.f;
#pragma unroll
    for (int mt = 0; mt < 4; ++mt) {
#pragma unroll
      for (int j = 0; j < 4; ++j) {
        v[mt * 4 + j] = __expf(s[r2][mt][j] + bb[r2][mt][j]);
        sum += v[mt * 4 + j];
      }
    }
    sum += __shfl_xor(sum, 16);
    sum += __shfl_xor(sum, 32);
    const float inv = (sum > 0.f) ? 1.0f / sum : 0.f;
#pragma unroll
    for (int mt = 0; mt < 4; ++mt)
      *reinterpret_cast<unsigned long long*>(LDS + QB + h * 8192 + sw128(r, (mt * 16 + g * 4) * 2)) =
          pack4(v[mt * 4] * inv, v[mt * 4 + 1] * inv, v[mt * 4 + 2] * inv, v[mt * 4 + 3] * inv);
  }

  // Phase 2c: O^T = V^T @ P^T; write ob (aliases XB; x dead since B2, P reads wave-local)
#pragma unroll
  for (int dt = 0; dt < 2; ++dt) {
#pragma unroll
    for (int r2 = 0; r2 < 2; ++r2) {
      const int r = (rt0 + r2) * 16 + c;
      f32x4 acc = {0.f, 0.f, 0.f, 0.f};
#pragma unroll
      for (int ks = 0; ks < 2; ++ks) {
        bf16x8 af = *reinterpret_cast<const bf16x8*>(LDS + VT + sw128(h * 32 + dt * 16 + c, (ks * 32 + g * 8) * 2));
        bf16x8 pf = *reinterpret_cast<const bf16x8*>(LDS + QB + h * 8192 + sw128(r, (ks * 32 + g * 8) * 2));
        acc = MFMA(af, pf, acc);
      }
      *reinterpret_cast<unsigned long long*>(LDS + XB + sw256(r, (h * 32 + dt * 16 + g * 4) * 2)) = pack4v(acc);
    }
  }
  __syncthreads();  // B4: ob visible

  // Phase 3: out^T = Wp @ O^T; f32x4 stores to global
  {
    bf16x8 ap[4];
    const unsigned short* wrow = wp + (w * 16 + c) * 128 + g * 8;
#pragma unroll
    for (int ks = 0; ks < 4; ++ks) ap[ks] = *reinterpret_cast<const bf16x8*>(wrow + ks * 32);
    f32x4 pb4 = *reinterpret_cast<const f32x4*>(proj_bias + w * 16 + g * 4);
    __builtin_amdgcn_s_setprio(1);
#pragma unroll
    for (int nt = 0; nt < 4; ++nt) {
      f32x4 acc = {0.f, 0.f, 0.f, 0.f};
#pragma unroll
      for (int ks = 0; ks < 4; ++ks) {
        bf16x8 bf = *reinterpret_cast<const bf16x8*>(LDS + XB + sw256(nt * 16 + c, (ks * 32 + g * 8) * 2));
        acc = MFMA(ap[ks], bf, acc);
      }
      const int tok = nt * 16 + c;
      if (tok < 49) {
        f32x4 o = {acc[0] + pb4[0], acc[1] + pb4[1], acc[2] + pb4[2], acc[3] + pb4[3]};
        *reinterpret_cast<f32x4*>(out + ((size_t)b * 49 + tok) * 128 + w * 16 + g * 4) = o;
      }
    }
    __builtin_amdgcn_s_setprio(0);
  }
}

extern "C" void kernel_launch(void* const* d_in, const int* in_sizes, int n_in,
                              void* d_out, int out_size, void* d_ws, size_t ws_size,
                              hipStream_t stream) {
  const float* x          = (const float*)d_in[0];
  const float* qk_w       = (const float*)d_in[1];
  const float* qk_b       = (const float*)d_in[2];
  const float* v_w        = (const float*)d_in[3];
  const float* v_b        = (const float*)d_in[4];
  const float* proj_w     = (const float*)d_in[5];
  const float* proj_b     = (const float*)d_in[6];
  const float* bias_table = (const float*)d_in[7];
  float* out = (float*)d_out;

  // workspace carve (196608 B): wqk bf16 [256*128] | wv [128*128] | wp [128*128] | biasNN f32 [4*64*64]
  unsigned short* wqk = (unsigned short*)d_ws;
  unsigned short* wv  = wqk + 256 * 128;
  unsigned short* wp  = wv + 128 * 128;
  float* biasNN = (float*)((char*)d_ws + 131072);

  const int B = in_sizes[0] / (49 * 128);

  rsa_prep<<<dim3(128), dim3(512), 0, stream>>>(qk_w, v_w, proj_w, bias_table, wqk, wv, wp, biasNN);
  rsa_main<<<dim3(B), dim3(512), 0, stream>>>(x, qk_b, v_b, proj_b, wqk, wv, wp, biasNN, out);
}